// Round 19
// baseline (135.838 us; speedup 1.0000x reference)
//
#include <hip/hip_runtime.h>

#define HID 512
#define SEQ 4096
#define NB 32
#define BS 64          // s-rows per chunk
#define NSB 16         // s-blocks per batch row (512 blocks total = 2/CU)
#define CPB 4          // chunks per block (NSB*CPB*BS = SEQ)
#define CH 514         // [m, den, num[512]]
#define TWO_LOG2E 2.88539008177793f   // 2*log2(e)

typedef __attribute__((ext_vector_type(8))) __bf16 bf16x8;
typedef __attribute__((ext_vector_type(4))) __bf16 bf16x4;
typedef __attribute__((ext_vector_type(16))) float f32x16;
typedef __attribute__((ext_vector_type(4))) float f32x4;

// ---- Kernel 1: build W1_a in MFMA-fragment order (h-tile ht, k-slice ks):
//      w1af[((ht*32+ks)*64 + lane)*8 + j] = bf16(W1a[k=ks*16+(lane>>5)*8+j][h=ht*32+(lane&31)])
__global__ void build_w1af(const float* __restrict__ W1,
                           unsigned short* __restrict__ w1af) {
    __shared__ float tile[64][65];
    int t = threadIdx.x;
    int lane = t & 63;
    int r4 = t >> 6;            // 0..3
    int k0 = blockIdx.x * 64;
    int h0 = blockIdx.y * 64;
#pragma unroll
    for (int i = 0; i < 16; ++i) {
        int r = i * 4 + r4;     // k-row within tile
        tile[r][lane] = W1[(size_t)(HID + k0 + r) * HID + h0 + lane];
    }
    __syncthreads();
#pragma unroll
    for (int i = 0; i < 16; ++i) {
        int hr = i * 4 + r4;    // h-row
        int h = h0 + hr, k = k0 + lane;
        __bf16 bv = (__bf16)tile[lane][hr];
        int ht = h >> 5, hl = h & 31;
        int ks = k >> 4, g = (k >> 3) & 1, j = k & 7;
        size_t off = (((size_t)ht * 32 + ks) * 64 + g * 32 + hl) * 8 + j;
        w1af[off] = *(unsigned short*)&bv;
    }
}

// ---- Kernel 2: pre_part[b][kc][h] = sum_{k in kc-chunk} prev[b][k]*W1_h[k][h] ----
__global__ void pre_partial(const float* __restrict__ prev,
                            const float* __restrict__ W1,
                            float* __restrict__ pre_part) {
    __shared__ float pl[128];
    int kc = blockIdx.x;   // 0..3
    int b  = blockIdx.y;
    int t  = threadIdx.x;
    if (t < 128) pl[t] = prev[b * HID + kc * 128 + t];
    __syncthreads();
    int h0 = 2 * t;
    float ax = 0.f, ay = 0.f;
    for (int k = 0; k < 128; ++k) {
        float pv = pl[k];
        float2 wv = *(const float2*)(W1 + (size_t)(kc * 128 + k) * HID + h0);
        ax += pv * wv.x;
        ay += pv * wv.y;
    }
    float* dst = pre_part + ((size_t)b * 4 + kc) * HID + h0;
    dst[0] = ax; dst[1] = ay;
}

// ---- Kernel 3: R18 base (stagger, 2/CU, algebraic epilogue) with:
//      plain (cacheable) ann loads for L3 retention, ~3.4us stagger sleep. ----
__global__ __launch_bounds__(256, 2)
void score_ctx(const float* __restrict__ ann,
               const unsigned short* __restrict__ w1af,
               const float* __restrict__ pre_part,
               const float* __restrict__ b1,
               const float* __restrict__ W2,
               float* __restrict__ cout) {
    __shared__ unsigned short buf[BS * 512];   // 64 KiB, XOR-swizzled bf16
    __shared__ float2 pw_lds[512];             // {pre*2log2e, w2}
    __shared__ float red[4][64];

    const int sb = blockIdx.x, b = blockIdx.y;
    const int t = threadIdx.x;
    const int wv = t >> 6;        // 0..3, wave owns h in [wv*128, wv*128+128)
    const int lane = t & 63;
    const int sl = lane & 31;
    const int g = lane >> 5;

    // ---- phase stagger: odd blocks sleep ~8K cycles (~3.4 us) ----
    if (((sb + b) & 1) != 0) {
        __builtin_amdgcn_s_sleep(127);
    }

#pragma unroll
    for (int j = 0; j < 2; ++j) {
        int h = t + j * 256;
        float pp = b1[h];
#pragma unroll
        for (int kc = 0; kc < 4; ++kc)
            pp += pre_part[((size_t)b * 4 + kc) * HID + h];
        pw_lds[h] = make_float2(pp * TWO_LOG2E, W2[h]);
    }
    __syncthreads();

    // ---- per-lane sum of w2 over this lane's 64 h's (16 r x 4 j), + other g ----
    float w2sum = 0.f;
#pragma unroll
    for (int r = 0; r < 16; ++r) {
        int hl = (r & 3) + 8 * (r >> 2) + 4 * g;
        int h0 = wv * 128 + hl;
        w2sum += pw_lds[h0].y + pw_lds[h0 + 32].y + pw_lds[h0 + 64].y + pw_lds[h0 + 96].y;
    }
    w2sum += __shfl_xor(w2sum, 32);   // both k-groups' h's

    const float* abase0 = ann + ((size_t)b * SEQ + (size_t)sb * (CPB * BS)) * 512;

    float m_run = -3.0e38f, d_run = 0.f;
    float ctxa = 0.f, ctxb = 0.f;

    const unsigned short* wb0 = w1af + (size_t)(4 * wv) * 16384 + (size_t)lane * 8;
    const unsigned short* wb1 = wb0 + 16384;
    const unsigned short* wb2 = wb0 + 32768;
    const unsigned short* wb3 = wb0 + 49152;
    const unsigned swz = (unsigned)(sl & 7) << 4;
    const unsigned rb0 = (unsigned)(( 0 + sl) * 1024 + g * 16);
    const unsigned rb1 = (unsigned)((32 + sl) * 1024 + g * 16);

#pragma unroll 1
    for (int c = 0; c < CPB; ++c) {
        __syncthreads();   // previous chunk's ctx readers done; buf reusable

        // ---- stage chunk c: 64 rows x 512 fp32 -> bf16 LDS (cacheable loads) ----
        const float* ab = abase0 + (size_t)c * BS * 512;
#pragma unroll 8
        for (int i = 0; i < 32; ++i) {
            int flat4 = t + i * 256;
            int row = flat4 >> 7, c4 = flat4 & 127;
            f32x4 f = *((const f32x4*)(ab) + flat4);
            bf16x4 pk;
            pk[0] = (__bf16)f[0]; pk[1] = (__bf16)f[1];
            pk[2] = (__bf16)f[2]; pk[3] = (__bf16)f[3];
            unsigned boff = ((unsigned)(row * 1024 + c4 * 8)) ^ ((unsigned)(row & 7) << 4);
            *(bf16x4*)((char*)buf + boff) = pk;
        }
        __syncthreads();

        // ---- K-loop: 4 h-tiles x 2 s-tiles, 8 MFMA per ks ----
        f32x16 c00, c01, c10, c11, c20, c21, c30, c31;
#pragma unroll
        for (int r = 0; r < 16; ++r) {
            c00[r] = 0.f; c01[r] = 0.f; c10[r] = 0.f; c11[r] = 0.f;
            c20[r] = 0.f; c21[r] = 0.f; c30[r] = 0.f; c31[r] = 0.f;
        }
#pragma unroll 2
        for (int ks = 0; ks < 32; ++ks) {
            bf16x8 A0 = *(const bf16x8*)(wb0 + ks * 512);
            bf16x8 A1 = *(const bf16x8*)(wb1 + ks * 512);
            bf16x8 A2 = *(const bf16x8*)(wb2 + ks * 512);
            bf16x8 A3 = *(const bf16x8*)(wb3 + ks * 512);
            unsigned kb = (unsigned)ks * 32u;
            bf16x8 B0 = *(const bf16x8*)((const char*)buf + ((rb0 + kb) ^ swz));
            bf16x8 B1 = *(const bf16x8*)((const char*)buf + ((rb1 + kb) ^ swz));
            c00 = __builtin_amdgcn_mfma_f32_32x32x16_bf16(A0, B0, c00, 0, 0, 0);
            c01 = __builtin_amdgcn_mfma_f32_32x32x16_bf16(A0, B1, c01, 0, 0, 0);
            c10 = __builtin_amdgcn_mfma_f32_32x32x16_bf16(A1, B0, c10, 0, 0, 0);
            c11 = __builtin_amdgcn_mfma_f32_32x32x16_bf16(A1, B1, c11, 0, 0, 0);
            c20 = __builtin_amdgcn_mfma_f32_32x32x16_bf16(A2, B0, c20, 0, 0, 0);
            c21 = __builtin_amdgcn_mfma_f32_32x32x16_bf16(A2, B1, c21, 0, 0, 0);
            c30 = __builtin_amdgcn_mfma_f32_32x32x16_bf16(A3, B0, c30, 0, 0, 0);
            c31 = __builtin_amdgcn_mfma_f32_32x32x16_bf16(A3, B1, c31, 0, 0, 0);
        }

        // ---- epilogue (algebraic): sp = w2sum - 2*sum w2*rcp(exp2(s)+1) ----
        float q0s = 0.f, q1s = 0.f;
#pragma unroll
        for (int r = 0; r < 16; ++r) {
            int hl = (r & 3) + 8 * (r >> 2) + 4 * g;
            int h0 = wv * 128 + hl;
            float2 q0 = pw_lds[h0];
            float2 q1 = pw_lds[h0 + 32];
            float2 q2 = pw_lds[h0 + 64];
            float2 q3 = pw_lds[h0 + 96];
            q0s += q0.y * __builtin_amdgcn_rcpf(__builtin_amdgcn_exp2f(fmaf(c00[r], TWO_LOG2E, q0.x)) + 1.f)
                 + q1.y * __builtin_amdgcn_rcpf(__builtin_amdgcn_exp2f(fmaf(c10[r], TWO_LOG2E, q1.x)) + 1.f)
                 + q2.y * __builtin_amdgcn_rcpf(__builtin_amdgcn_exp2f(fmaf(c20[r], TWO_LOG2E, q2.x)) + 1.f)
                 + q3.y * __builtin_amdgcn_rcpf(__builtin_amdgcn_exp2f(fmaf(c30[r], TWO_LOG2E, q3.x)) + 1.f);
            q1s += q0.y * __builtin_amdgcn_rcpf(__builtin_amdgcn_exp2f(fmaf(c01[r], TWO_LOG2E, q0.x)) + 1.f)
                 + q1.y * __builtin_amdgcn_rcpf(__builtin_amdgcn_exp2f(fmaf(c11[r], TWO_LOG2E, q1.x)) + 1.f)
                 + q2.y * __builtin_amdgcn_rcpf(__builtin_amdgcn_exp2f(fmaf(c21[r], TWO_LOG2E, q2.x)) + 1.f)
                 + q3.y * __builtin_amdgcn_rcpf(__builtin_amdgcn_exp2f(fmaf(c31[r], TWO_LOG2E, q3.x)) + 1.f);
        }
        float sp0 = -2.f * (q0s + __shfl_xor(q0s, 32));
        float sp1 = -2.f * (q1s + __shfl_xor(q1s, 32));
        sp0 += w2sum;
        sp1 += w2sum;
        if (lane < 32) { red[wv][sl] = sp0; red[wv][32 + sl] = sp1; }
        __syncthreads();

        // ---- softmax: all waves redundantly (score for s = lane) ----
        float sc = red[0][lane] + red[1][lane] + red[2][lane] + red[3][lane];
        float m = sc;
#pragma unroll
        for (int off = 32; off; off >>= 1) m = fmaxf(m, __shfl_xor(m, off));
        float p = __expf(sc - m);
        float d = p;
#pragma unroll
        for (int off = 32; off; off >>= 1) d += __shfl_xor(d, off);

        float m_new = fmaxf(m_run, m);
        float so = __expf(m_run - m_new), s_c = __expf(m - m_new);
        d_run = d_run * so + d * s_c;

        // ---- ctx numerator: thread t owns cols 2t, 2t+1; p broadcast via shfl ----
        float na = 0.f, nb = 0.f;
#pragma unroll 16
        for (int s = 0; s < BS; ++s) {
            float ps = __shfl(p, s);
            unsigned boff = ((unsigned)(s * 1024 + 4 * t)) ^ ((unsigned)(s & 7) << 4);
            unsigned u = *(const unsigned*)((const char*)buf + boff);
            na += ps * __uint_as_float(u << 16);
            nb += ps * __uint_as_float(u & 0xFFFF0000u);
        }
        ctxa = ctxa * so + na * s_c;
        ctxb = ctxb * so + nb * s_c;
        m_run = m_new;
    }

    float* cb = cout + ((size_t)b * NSB + sb) * CH;
    cb[2 + 2 * t]     = ctxa;
    cb[2 + 2 * t + 1] = ctxb;
    if (t == 0) { cb[0] = m_run; cb[1] = d_run; }
}

// ---- Kernel 4: merge 16 s-block partials per batch row ----
__global__ void finalize_ctx(const float* __restrict__ cout,
                             float* __restrict__ out) {
    int b = blockIdx.x, t = threadIdx.x;   // 512 threads
    float ms[NSB];
    float M = -3.0e38f;
#pragma unroll
    for (int s = 0; s < NSB; ++s) {
        ms[s] = cout[((size_t)b * NSB + s) * CH];
        M = fmaxf(M, ms[s]);
    }
    float D = 0.f, val = 0.f;
#pragma unroll
    for (int s = 0; s < NSB; ++s) {
        const float* cb = cout + ((size_t)b * NSB + s) * CH;
        float e = __expf(ms[s] - M);
        D += e * cb[1];
        val += e * cb[2 + t];
    }
    out[(size_t)b * 512 + t] = val / D;
}

extern "C" void kernel_launch(void* const* d_in, const int* in_sizes, int n_in,
                              void* d_out, int out_size, void* d_ws, size_t ws_size,
                              hipStream_t stream) {
    (void)in_sizes; (void)n_in; (void)out_size; (void)ws_size;
    const float* prev = (const float*)d_in[0];
    const float* ann  = (const float*)d_in[1];
    const float* W1   = (const float*)d_in[2];
    const float* b1   = (const float*)d_in[3];
    const float* W2   = (const float*)d_in[4];
    // b2 (d_in[5]) cancels in softmax; unused.
    float* out = (float*)d_out;

    char* ws = (char*)d_ws;
    unsigned short* w1af = (unsigned short*)ws;               // 512*512*2 = 524288 B
    float* pre_part = (float*)(ws + 524288);                  // 32*4*512*4 = 262144 B
    float* cout     = (float*)(ws + 524288 + 262144);         // 32*16*514*4 = 1052672 B

    build_w1af<<<dim3(8, 8), dim3(256), 0, stream>>>(W1, w1af);
    pre_partial<<<dim3(4, NB), dim3(256), 0, stream>>>(prev, W1, pre_part);
    score_ctx<<<dim3(NSB, NB), dim3(256), 0, stream>>>(ann, w1af, pre_part, b1, W2, cout);
    finalize_ctx<<<dim3(NB), dim3(512), 0, stream>>>(cout, out);
}

// Round 20
// 123.942 us; speedup vs baseline: 1.0960x; 1.0960x over previous
//
#include <hip/hip_runtime.h>

#define HID 512
#define SEQ 4096
#define NB 32
#define BS 64          // s-rows per chunk
#define NSB 16         // s-blocks per batch row (512 blocks total = 2/CU)
#define CPB 4          // chunks per block (NSB*CPB*BS = SEQ)
#define CH 514         // [m, den, num[512]]
#define TWO_LOG2E 2.88539008177793f   // 2*log2(e)

typedef __attribute__((ext_vector_type(8))) __bf16 bf16x8;
typedef __attribute__((ext_vector_type(4))) __bf16 bf16x4;
typedef __attribute__((ext_vector_type(16))) float f32x16;
typedef __attribute__((ext_vector_type(4))) float f32x4;

// ---- Kernel 1: build W1_a in MFMA-fragment order (h-tile ht, k-slice ks):
//      w1af[((ht*32+ks)*64 + lane)*8 + j] = bf16(W1a[k=ks*16+(lane>>5)*8+j][h=ht*32+(lane&31)])
__global__ void build_w1af(const float* __restrict__ W1,
                           unsigned short* __restrict__ w1af) {
    __shared__ float tile[64][65];
    int t = threadIdx.x;
    int lane = t & 63;
    int r4 = t >> 6;            // 0..3
    int k0 = blockIdx.x * 64;
    int h0 = blockIdx.y * 64;
#pragma unroll
    for (int i = 0; i < 16; ++i) {
        int r = i * 4 + r4;     // k-row within tile
        tile[r][lane] = W1[(size_t)(HID + k0 + r) * HID + h0 + lane];
    }
    __syncthreads();
#pragma unroll
    for (int i = 0; i < 16; ++i) {
        int hr = i * 4 + r4;    // h-row
        int h = h0 + hr, k = k0 + lane;
        __bf16 bv = (__bf16)tile[lane][hr];
        int ht = h >> 5, hl = h & 31;
        int ks = k >> 4, g = (k >> 3) & 1, j = k & 7;
        size_t off = (((size_t)ht * 32 + ks) * 64 + g * 32 + hl) * 8 + j;
        w1af[off] = *(unsigned short*)&bv;
    }
}

// ---- Kernel 2: pre_part[b][kc][h] = sum_{k in kc-chunk} prev[b][k]*W1_h[k][h] ----
__global__ void pre_partial(const float* __restrict__ prev,
                            const float* __restrict__ W1,
                            float* __restrict__ pre_part) {
    __shared__ float pl[128];
    int kc = blockIdx.x;   // 0..3
    int b  = blockIdx.y;
    int t  = threadIdx.x;
    if (t < 128) pl[t] = prev[b * HID + kc * 128 + t];
    __syncthreads();
    int h0 = 2 * t;
    float ax = 0.f, ay = 0.f;
    for (int k = 0; k < 128; ++k) {
        float pv = pl[k];
        float2 wv = *(const float2*)(W1 + (size_t)(kc * 128 + k) * HID + h0);
        ax += pv * wv.x;
        ay += pv * wv.y;
    }
    float* dst = pre_part + ((size_t)b * 4 + kc) * HID + h0;
    dst[0] = ax; dst[1] = ay;
}

// ---- Kernel 3: R18 exact restore (measured 124.1 us): stagger 2/CU,
//      NT staging loads (protect W-panel in L2), algebraic epilogue. ----
__global__ __launch_bounds__(256, 2)
void score_ctx(const float* __restrict__ ann,
               const unsigned short* __restrict__ w1af,
               const float* __restrict__ pre_part,
               const float* __restrict__ b1,
               const float* __restrict__ W2,
               float* __restrict__ cout) {
    __shared__ unsigned short buf[BS * 512];   // 64 KiB, XOR-swizzled bf16
    __shared__ float2 pw_lds[512];             // {pre*2log2e, w2}
    __shared__ float red[4][64];

    const int sb = blockIdx.x, b = blockIdx.y;
    const int t = threadIdx.x;
    const int wv = t >> 6;        // 0..3, wave owns h in [wv*128, wv*128+128)
    const int lane = t & 63;
    const int sl = lane & 31;
    const int g = lane >> 5;

    // ---- phase stagger: odd blocks sleep ~16K cycles (~7 us) ----
    if (((sb + b) & 1) != 0) {
        __builtin_amdgcn_s_sleep(127);
        __builtin_amdgcn_s_sleep(127);
    }

#pragma unroll
    for (int j = 0; j < 2; ++j) {
        int h = t + j * 256;
        float pp = b1[h];
#pragma unroll
        for (int kc = 0; kc < 4; ++kc)
            pp += pre_part[((size_t)b * 4 + kc) * HID + h];
        pw_lds[h] = make_float2(pp * TWO_LOG2E, W2[h]);
    }
    __syncthreads();

    // ---- per-lane sum of w2 over this lane's 64 h's (16 r x 4 j), + other g ----
    float w2sum = 0.f;
#pragma unroll
    for (int r = 0; r < 16; ++r) {
        int hl = (r & 3) + 8 * (r >> 2) + 4 * g;
        int h0 = wv * 128 + hl;
        w2sum += pw_lds[h0].y + pw_lds[h0 + 32].y + pw_lds[h0 + 64].y + pw_lds[h0 + 96].y;
    }
    w2sum += __shfl_xor(w2sum, 32);   // both k-groups' h's

    const float* abase0 = ann + ((size_t)b * SEQ + (size_t)sb * (CPB * BS)) * 512;

    float m_run = -3.0e38f, d_run = 0.f;
    float ctxa = 0.f, ctxb = 0.f;

    const unsigned short* wb0 = w1af + (size_t)(4 * wv) * 16384 + (size_t)lane * 8;
    const unsigned short* wb1 = wb0 + 16384;
    const unsigned short* wb2 = wb0 + 32768;
    const unsigned short* wb3 = wb0 + 49152;
    const unsigned swz = (unsigned)(sl & 7) << 4;
    const unsigned rb0 = (unsigned)(( 0 + sl) * 1024 + g * 16);
    const unsigned rb1 = (unsigned)((32 + sl) * 1024 + g * 16);

#pragma unroll 1
    for (int c = 0; c < CPB; ++c) {
        __syncthreads();   // previous chunk's ctx readers done; buf reusable

        // ---- stage chunk c: 64 rows x 512 fp32 -> bf16 LDS (NT loads) ----
        const float* ab = abase0 + (size_t)c * BS * 512;
#pragma unroll 8
        for (int i = 0; i < 32; ++i) {
            int flat4 = t + i * 256;
            int row = flat4 >> 7, c4 = flat4 & 127;
            f32x4 f = __builtin_nontemporal_load((const f32x4*)(ab) + flat4);
            bf16x4 pk;
            pk[0] = (__bf16)f[0]; pk[1] = (__bf16)f[1];
            pk[2] = (__bf16)f[2]; pk[3] = (__bf16)f[3];
            unsigned boff = ((unsigned)(row * 1024 + c4 * 8)) ^ ((unsigned)(row & 7) << 4);
            *(bf16x4*)((char*)buf + boff) = pk;
        }
        __syncthreads();

        // ---- K-loop: 4 h-tiles x 2 s-tiles, 8 MFMA per ks ----
        f32x16 c00, c01, c10, c11, c20, c21, c30, c31;
#pragma unroll
        for (int r = 0; r < 16; ++r) {
            c00[r] = 0.f; c01[r] = 0.f; c10[r] = 0.f; c11[r] = 0.f;
            c20[r] = 0.f; c21[r] = 0.f; c30[r] = 0.f; c31[r] = 0.f;
        }
#pragma unroll 2
        for (int ks = 0; ks < 32; ++ks) {
            bf16x8 A0 = *(const bf16x8*)(wb0 + ks * 512);
            bf16x8 A1 = *(const bf16x8*)(wb1 + ks * 512);
            bf16x8 A2 = *(const bf16x8*)(wb2 + ks * 512);
            bf16x8 A3 = *(const bf16x8*)(wb3 + ks * 512);
            unsigned kb = (unsigned)ks * 32u;
            bf16x8 B0 = *(const bf16x8*)((const char*)buf + ((rb0 + kb) ^ swz));
            bf16x8 B1 = *(const bf16x8*)((const char*)buf + ((rb1 + kb) ^ swz));
            c00 = __builtin_amdgcn_mfma_f32_32x32x16_bf16(A0, B0, c00, 0, 0, 0);
            c01 = __builtin_amdgcn_mfma_f32_32x32x16_bf16(A0, B1, c01, 0, 0, 0);
            c10 = __builtin_amdgcn_mfma_f32_32x32x16_bf16(A1, B0, c10, 0, 0, 0);
            c11 = __builtin_amdgcn_mfma_f32_32x32x16_bf16(A1, B1, c11, 0, 0, 0);
            c20 = __builtin_amdgcn_mfma_f32_32x32x16_bf16(A2, B0, c20, 0, 0, 0);
            c21 = __builtin_amdgcn_mfma_f32_32x32x16_bf16(A2, B1, c21, 0, 0, 0);
            c30 = __builtin_amdgcn_mfma_f32_32x32x16_bf16(A3, B0, c30, 0, 0, 0);
            c31 = __builtin_amdgcn_mfma_f32_32x32x16_bf16(A3, B1, c31, 0, 0, 0);
        }

        // ---- epilogue (algebraic): sp = w2sum - 2*sum w2*rcp(exp2(s)+1),
        //      s = acc*2log2e + pre2  (pre2 = pre*2log2e from LDS) ----
        float q0s = 0.f, q1s = 0.f;
#pragma unroll
        for (int r = 0; r < 16; ++r) {
            int hl = (r & 3) + 8 * (r >> 2) + 4 * g;
            int h0 = wv * 128 + hl;
            float2 q0 = pw_lds[h0];
            float2 q1 = pw_lds[h0 + 32];
            float2 q2 = pw_lds[h0 + 64];
            float2 q3 = pw_lds[h0 + 96];
            q0s += q0.y * __builtin_amdgcn_rcpf(__builtin_amdgcn_exp2f(fmaf(c00[r], TWO_LOG2E, q0.x)) + 1.f)
                 + q1.y * __builtin_amdgcn_rcpf(__builtin_amdgcn_exp2f(fmaf(c10[r], TWO_LOG2E, q1.x)) + 1.f)
                 + q2.y * __builtin_amdgcn_rcpf(__builtin_amdgcn_exp2f(fmaf(c20[r], TWO_LOG2E, q2.x)) + 1.f)
                 + q3.y * __builtin_amdgcn_rcpf(__builtin_amdgcn_exp2f(fmaf(c30[r], TWO_LOG2E, q3.x)) + 1.f);
            q1s += q0.y * __builtin_amdgcn_rcpf(__builtin_amdgcn_exp2f(fmaf(c01[r], TWO_LOG2E, q0.x)) + 1.f)
                 + q1.y * __builtin_amdgcn_rcpf(__builtin_amdgcn_exp2f(fmaf(c11[r], TWO_LOG2E, q1.x)) + 1.f)
                 + q2.y * __builtin_amdgcn_rcpf(__builtin_amdgcn_exp2f(fmaf(c21[r], TWO_LOG2E, q2.x)) + 1.f)
                 + q3.y * __builtin_amdgcn_rcpf(__builtin_amdgcn_exp2f(fmaf(c31[r], TWO_LOG2E, q3.x)) + 1.f);
        }
        float sp0 = -2.f * (q0s + __shfl_xor(q0s, 32));
        float sp1 = -2.f * (q1s + __shfl_xor(q1s, 32));
        sp0 += w2sum;
        sp1 += w2sum;
        if (lane < 32) { red[wv][sl] = sp0; red[wv][32 + sl] = sp1; }
        __syncthreads();

        // ---- softmax: all waves redundantly (score for s = lane) ----
        float sc = red[0][lane] + red[1][lane] + red[2][lane] + red[3][lane];
        float m = sc;
#pragma unroll
        for (int off = 32; off; off >>= 1) m = fmaxf(m, __shfl_xor(m, off));
        float p = __expf(sc - m);
        float d = p;
#pragma unroll
        for (int off = 32; off; off >>= 1) d += __shfl_xor(d, off);

        float m_new = fmaxf(m_run, m);
        float so = __expf(m_run - m_new), s_c = __expf(m - m_new);
        d_run = d_run * so + d * s_c;

        // ---- ctx numerator: thread t owns cols 2t, 2t+1; p broadcast via shfl ----
        float na = 0.f, nb = 0.f;
#pragma unroll 8
        for (int s = 0; s < BS; ++s) {
            float ps = __shfl(p, s);
            unsigned boff = ((unsigned)(s * 1024 + 4 * t)) ^ ((unsigned)(s & 7) << 4);
            unsigned u = *(const unsigned*)((const char*)buf + boff);
            na += ps * __uint_as_float(u << 16);
            nb += ps * __uint_as_float(u & 0xFFFF0000u);
        }
        ctxa = ctxa * so + na * s_c;
        ctxb = ctxb * so + nb * s_c;
        m_run = m_new;
    }

    float* cb = cout + ((size_t)b * NSB + sb) * CH;
    cb[2 + 2 * t]     = ctxa;
    cb[2 + 2 * t + 1] = ctxb;
    if (t == 0) { cb[0] = m_run; cb[1] = d_run; }
}

// ---- Kernel 4: merge 16 s-block partials per batch row ----
__global__ void finalize_ctx(const float* __restrict__ cout,
                             float* __restrict__ out) {
    int b = blockIdx.x, t = threadIdx.x;   // 512 threads
    float ms[NSB];
    float M = -3.0e38f;
#pragma unroll
    for (int s = 0; s < NSB; ++s) {
        ms[s] = cout[((size_t)b * NSB + s) * CH];
        M = fmaxf(M, ms[s]);
    }
    float D = 0.f, val = 0.f;
#pragma unroll
    for (int s = 0; s < NSB; ++s) {
        const float* cb = cout + ((size_t)b * NSB + s) * CH;
        float e = __expf(ms[s] - M);
        D += e * cb[1];
        val += e * cb[2 + t];
    }
    out[(size_t)b * 512 + t] = val / D;
}

extern "C" void kernel_launch(void* const* d_in, const int* in_sizes, int n_in,
                              void* d_out, int out_size, void* d_ws, size_t ws_size,
                              hipStream_t stream) {
    (void)in_sizes; (void)n_in; (void)out_size; (void)ws_size;
    const float* prev = (const float*)d_in[0];
    const float* ann  = (const float*)d_in[1];
    const float* W1   = (const float*)d_in[2];
    const float* b1   = (const float*)d_in[3];
    const float* W2   = (const float*)d_in[4];
    // b2 (d_in[5]) cancels in softmax; unused.
    float* out = (float*)d_out;

    char* ws = (char*)d_ws;
    unsigned short* w1af = (unsigned short*)ws;               // 512*512*2 = 524288 B
    float* pre_part = (float*)(ws + 524288);                  // 32*4*512*4 = 262144 B
    float* cout     = (float*)(ws + 524288 + 262144);         // 32*16*514*4 = 1052672 B

    build_w1af<<<dim3(8, 8), dim3(256), 0, stream>>>(W1, w1af);
    pre_partial<<<dim3(4, NB), dim3(256), 0, stream>>>(prev, W1, pre_part);
    score_ctx<<<dim3(NSB, NB), dim3(256), 0, stream>>>(ann, w1af, pre_part, b1, W2, cout);
    finalize_ctx<<<dim3(NB), dim3(512), 0, stream>>>(cout, out);
}